// Round 21
// baseline (269.236 us; speedup 1.0000x reference)
//
#include <hip/hip_runtime.h>
#include <math.h>

#define TOPK 8
#define NE   128
#define MARGIN 1e-5f

typedef _Float16 h8 __attribute__((ext_vector_type(8)));
typedef _Float16 h4 __attribute__((ext_vector_type(4)));
typedef float    f4 __attribute__((ext_vector_type(4)));

// Row-pair-packed swizzled byte address for a [rows][32 halfs] (64B-row) tile.
// Two rows share a 128-B line; XOR spreads the 8 16-B slots. 16-lane column
// reads -> 2-way bank aliasing only (free). (R10-correctness-validated)
__device__ __forceinline__ int adr(int row, int kb) {
  const int line = row >> 1;
  return line * 128 + ((((row & 1) << 6) | kb) ^ ((line & 7) << 4));
}

#define GLOAD_LDS16(g, l)                                              \
  __builtin_amdgcn_global_load_lds(                                    \
      (const __attribute__((address_space(1))) void*)(g),              \
      (__attribute__((address_space(3))) void*)(l), 16, 0, 0)

// ---------------- Kernel 0: split W into fp16 hi + scaled lo ----------------
__global__ __launch_bounds__(256) void router_wsplit(
    const float* __restrict__ W, _Float16* __restrict__ whi,
    _Float16* __restrict__ wlo, int n4) {
  const int i = blockIdx.x * 256 + threadIdx.x;
  if (i < n4) {
    const float4 v = ((const float4*)W)[i];
    h4 hi, lo;
#pragma unroll
    for (int q = 0; q < 4; ++q) {
      const float vq = ((const float*)&v)[q];
      const _Float16 h = (_Float16)vq;
      hi[q] = h;
      lo[q] = (_Float16)((vq - (float)h) * 2048.0f);  // lo' = lo * 2^11
    }
    ((h4*)whi)[i] = hi;
    ((h4*)wlo)[i] = lo;
  }
}

// ---------------- Pass 1: split-fp16 MFMA GEMM; BK=32, A+B dbuf, 1 barrier/tile ----------------
// 512 threads = 8 waves; tile 64 tok x 128 exp; 48KB LDS -> 3 blocks/CU (24 waves).
// LDS: A buf0 hi@0 lo@4096, buf1 hi@8192 lo@12288; B buf0 hi@16384 lo@24576,
//      buf1 hi@32768 lo@40960. Epilogue: logits [64][132] f32 @0, flg @33792.
__global__ __launch_bounds__(512, 6) void router_pass1(
    const float* __restrict__ x,        // [T, H] fp32
    const _Float16* __restrict__ whi,   // [E, H] fp16
    const _Float16* __restrict__ wlo,   // [E, H] fp16 (x 2^11)
    const float* __restrict__ bias,
    float* __restrict__ out_w, float* __restrict__ out_i,
    unsigned int* __restrict__ mask, int T, int H) {
  __shared__ char lds[49152];

  const int tid = threadIdx.x;
  const int t0  = blockIdx.x * 64;
  const int l   = tid & 63;
  const int wv  = tid >> 6;            // 0..7
  const int wm  = wv & 1;              // token half (32)
  const int wn  = wv >> 1;             // expert quarter (32)

  // x: thread -> row tid>>3 (0..63), float-quad (tid&7)*4 within K32 tile
  const float* xptr = x + (size_t)(t0 + (tid >> 3)) * H + (tid & 7) * 4;
  const int awA = adr(tid >> 3, (tid & 7) * 8);   // A write byte addr (8B granule)

  // B DMA: linear dest offset o = tid*16 over an 8KB component; pre-swizzled
  // global source offset (inverse of adr; R10-validated pair).
  int soff;
  {
    const int o    = tid * 16;
    const int line = o >> 7;
    const int un   = (o & 127) ^ ((line & 7) << 4);
    soff = (line * 2 + (un >> 6)) * (H * 2) + (un & 63);
  }
  const int wvbase = wv * 1024;        // wave-uniform LDS dest base offset

  f4 acc1[2][2], acc2[2][2];
#pragma unroll
  for (int mt = 0; mt < 2; ++mt)
#pragma unroll
    for (int nt = 0; nt < 2; ++nt) { acc1[mt][nt] = (f4)0.0f; acc2[mt][nt] = (f4)0.0f; }

  // ---- prologue: WDMA tile0 -> B buf0; convert+write A tile0; px <- tile1 ----
  GLOAD_LDS16((const char*)whi + soff, lds + 16384 + wvbase);
  GLOAD_LDS16((const char*)wlo + soff, lds + 24576 + wvbase);
  float4 px = *(const float4*)(xptr);
  {
    const float* pv = (const float*)&px;
    h4 hi4, lo4;
#pragma unroll
    for (int q = 0; q < 4; ++q) {
      const _Float16 hh = (_Float16)pv[q];
      hi4[q] = hh;
      lo4[q] = (_Float16)((pv[q] - (float)hh) * 2048.0f);
    }
    *(h4*)(lds + awA)        = hi4;    // A buf0 hi
    *(h4*)(lds + 4096 + awA) = lo4;    // A buf0 lo
  }
  px = *(const float4*)(xptr + 32);    // tile 1

#define ITER(K0, CUR)                                                         \
  {                                                                           \
    /* barrier: drain WDMA(K0) (keep newest px in flight); A writes visible */\
    if ((K0) + 32 < H)                                                        \
      asm volatile("s_waitcnt vmcnt(1) lgkmcnt(0)" ::: "memory");             \
    else                                                                      \
      asm volatile("s_waitcnt vmcnt(0) lgkmcnt(0)" ::: "memory");             \
    __builtin_amdgcn_s_barrier();                                             \
    __builtin_amdgcn_sched_barrier(0);                                        \
    if ((K0) + 32 < H) {                                                      \
      /* issue WDMA(K0+32) -> B[CUR^1] (drained at NEXT barrier) */           \
      const char* whb = (const char*)whi + (size_t)((K0) + 32) * 2;           \
      const char* wlb = (const char*)wlo + (size_t)((K0) + 32) * 2;           \
      const int nb = 16384 + ((CUR) ^ 1) * 16384;                             \
      GLOAD_LDS16(whb + soff, lds + nb + wvbase);                             \
      GLOAD_LDS16(wlb + soff, lds + nb + 8192 + wvbase);                      \
      /* convert px (tile K0+32) -> A[CUR^1] */                               \
      const float* pv = (const float*)&px;                                    \
      h4 hi4, lo4;                                                            \
      _Pragma("unroll")                                                       \
      for (int q = 0; q < 4; ++q) {                                           \
        const _Float16 hh = (_Float16)pv[q];                                  \
        hi4[q] = hh;                                                          \
        lo4[q] = (_Float16)((pv[q] - (float)hh) * 2048.0f);                   \
      }                                                                       \
      const int ab = ((CUR) ^ 1) * 8192;                                      \
      *(h4*)(lds + ab + awA)        = hi4;                                    \
      *(h4*)(lds + ab + 4096 + awA) = lo4;                                    \
    }                                                                         \
    /* reload px 2 tiles ahead */                                             \
    if ((K0) + 64 < H) px = *(const float4*)(xptr + (K0) + 64);               \
    /* MFMA(K0) from A[CUR] + B[CUR] */                                       \
    {                                                                         \
      const int abase = (CUR) * 8192;                                         \
      const int bbase = 16384 + (CUR) * 16384;                                \
      const int kbb = (l >> 4) * 16;                                          \
      h8 Ah[2], Al[2];                                                        \
      _Pragma("unroll")                                                       \
      for (int mt = 0; mt < 2; ++mt) {                                        \
        const int row = wm * 32 + mt * 16 + (l & 15);                         \
        Ah[mt] = *(const h8*)(lds + abase +        adr(row, kbb));            \
        Al[mt] = *(const h8*)(lds + abase + 4096 + adr(row, kbb));            \
      }                                                                       \
      _Pragma("unroll")                                                       \
      for (int nt = 0; nt < 2; ++nt) {                                        \
        const int er = wn * 32 + nt * 16 + (l & 15);                          \
        const h8 Bh = *(const h8*)(lds + bbase +        adr(er, kbb));        \
        const h8 Bl = *(const h8*)(lds + bbase + 8192 + adr(er, kbb));        \
        _Pragma("unroll")                                                     \
        for (int mt = 0; mt < 2; ++mt) {                                      \
          acc1[mt][nt] = __builtin_amdgcn_mfma_f32_16x16x32_f16(Ah[mt], Bh, acc1[mt][nt], 0, 0, 0); \
          acc2[mt][nt] = __builtin_amdgcn_mfma_f32_16x16x32_f16(Ah[mt], Bl, acc2[mt][nt], 0, 0, 0); \
          acc2[mt][nt] = __builtin_amdgcn_mfma_f32_16x16x32_f16(Al[mt], Bh, acc2[mt][nt], 0, 0, 0); \
        }                                                                     \
      }                                                                       \
    }                                                                         \
  }

  for (int k0 = 0; k0 < H; k0 += 64) {
    ITER(k0,      0)
    ITER(k0 + 32, 1)
  }
#undef ITER

  // ---- dump logits to LDS (C/D layout: col=lane&15, row=(lane>>4)*4+r) ----
  __syncthreads();
  float* logits = (float*)lds;
  unsigned char* flg = (unsigned char*)(lds + 33792);
#pragma unroll
  for (int mt = 0; mt < 2; ++mt)
#pragma unroll
    for (int nt = 0; nt < 2; ++nt)
#pragma unroll
      for (int r = 0; r < 4; ++r) {
        const int row = wm * 32 + mt * 16 + (l >> 4) * 4 + r;
        const int col = wn * 32 + nt * 16 + (l & 15);
        logits[row * 132 + col] = acc1[mt][nt][r] + acc2[mt][nt][r] * (1.0f / 2048.0f);
      }
  __syncthreads();

  // ---- epilogue: sigmoid, top-8 across 16-lane groups, flag near-ties ----
  const int tx    = tid & 15;
  const int g     = tid >> 4;          // 32 groups x 2 tokens
  const int lane  = tid & 63;
  const int gbase = lane & 48;

  float biasr[8];
#pragma unroll
  for (int j = 0; j < 4; ++j) {
    biasr[j]     = bias[tx * 4 + j];
    biasr[4 + j] = bias[64 + tx * 4 + j];
  }

#pragma unroll
  for (int it = 0; it < 2; ++it) {
    const int tok = g * 2 + it;
    const float4 lo4 = *(const float4*)(logits + tok * 132 + tx * 4);
    const float4 hi4 = *(const float4*)(logits + tok * 132 + 64 + tx * 4);
    float sc[8], bal[8];
#pragma unroll
    for (int j = 0; j < 4; ++j) {
      sc[j]     = 1.f / (1.f + expf(-((const float*)&lo4)[j]));
      sc[4 + j] = 1.f / (1.f + expf(-((const float*)&hi4)[j]));
    }
#pragma unroll
    for (int j = 0; j < 8; ++j) bal[j] = sc[j] + biasr[j];

    float myw[TOPK];
    int   myid[TOPK];
    float prev = 0.f;
    int   flagged = 0;
#pragma unroll
    for (int r = 0; r < TOPK + 1; ++r) {
      float bv = bal[0];
      int   bi = tx * 4;
#pragma unroll
      for (int j = 1; j < 8; ++j) {
        const int ej = (j < 4) ? (tx * 4 + j) : (64 + tx * 4 + (j - 4));
        if (bal[j] > bv) { bv = bal[j]; bi = ej; }
      }
#pragma unroll
      for (int m = 1; m <= 8; m <<= 1) {
        const float ov = __shfl_xor(bv, m);
        const int   oi = __shfl_xor(bi, m);
        if (ov > bv || (ov == bv && oi < bi)) { bv = ov; bi = oi; }
      }
      if (r > 0 && (prev - bv) < MARGIN) flagged = 1;
      prev = bv;
      if (r < TOPK) {
        const int ls = (bi < 64) ? (bi >> 2) : ((bi - 64) >> 2);
        const int jt = (bi < 64) ? (bi & 3) : (4 + ((bi - 64) & 3));
        const float a0s = (jt & 1) ? sc[1] : sc[0];
        const float a1s = (jt & 1) ? sc[3] : sc[2];
        const float a2s = (jt & 1) ? sc[5] : sc[4];
        const float a3s = (jt & 1) ? sc[7] : sc[6];
        const float b0s = (jt & 2) ? a1s : a0s;
        const float b1s = (jt & 2) ? a3s : a2s;
        const float sv = (jt & 4) ? b1s : b0s;
        const float sw = __shfl(sv, gbase | ls);
        myw[r]  = sw;
        myid[r] = bi;
#pragma unroll
        for (int j = 0; j < 8; ++j)
          if (tx == ls && j == jt) bal[j] = -INFINITY;
      }
    }

    if (tx == 0) {
      float den = 0.f;
#pragma unroll
      for (int r = 0; r < TOPK; ++r) den += fabsf(myw[r]);
      den = fmaxf(den, 1e-12f);
      const int t = t0 + tok;
      float4* wo = (float4*)(out_w + (size_t)t * TOPK);
      float4* io = (float4*)(out_i + (size_t)t * TOPK);
      wo[0] = make_float4(myw[0] / den, myw[1] / den, myw[2] / den, myw[3] / den);
      wo[1] = make_float4(myw[4] / den, myw[5] / den, myw[6] / den, myw[7] / den);
      io[0] = make_float4((float)myid[0], (float)myid[1], (float)myid[2], (float)myid[3]);
      io[1] = make_float4((float)myid[4], (float)myid[5], (float)myid[6], (float)myid[7]);
      flg[tok] = (unsigned char)flagged;
    }
  }

  // ---- assemble and store this block's two mask words (no atomics) ----
  __syncthreads();
  if (tid < 2) {
    unsigned int wbits = 0;
#pragma unroll
    for (int b = 0; b < 32; ++b)
      wbits |= (flg[tid * 32 + b] ? 1u : 0u) << b;
    mask[blockIdx.x * 2 + tid] = wbits;
  }
}

// ---------------- Compaction: bitmask -> ordered token list (deterministic) ----------------
__global__ __launch_bounds__(1024) void router_compact(
    const unsigned int* __restrict__ mask, int* __restrict__ cnt,
    int* __restrict__ flags, int nwords) {
  __shared__ int wsum[17];
  const int tid = threadIdx.x;
  unsigned int w = (tid < nwords) ? mask[tid] : 0u;
  const int c = __popc(w);
  const int lane = tid & 63;
  const int wv   = tid >> 6;
  int inc = c;
#pragma unroll
  for (int m = 1; m < 64; m <<= 1) {
    const int v = __shfl_up(inc, m);
    if (lane >= m) inc += v;
  }
  if (lane == 63) wsum[wv + 1] = inc;
  __syncthreads();
  if (tid == 0) {
    wsum[0] = 0;
    for (int i = 1; i <= 16; ++i) wsum[i] += wsum[i - 1];
    cnt[0] = wsum[16];
  }
  __syncthreads();
  int off = wsum[wv] + inc - c;
  while (w) {
    const int b = __ffs(w) - 1;
    w &= w - 1u;
    flags[off++] = tid * 32 + b;
  }
}

// ---------------- Pass 2: fp64 recompute, ONE token per block (grid-stride) ----------------
__global__ __launch_bounds__(256) void router_pass2(
    const float* __restrict__ x, const float* __restrict__ W,
    const float* __restrict__ bias,
    float* __restrict__ out_w, float* __restrict__ out_i,
    const int* __restrict__ cnt, const int* __restrict__ flags, int H) {
  __shared__ float  xs[4096];          // 16 KB (H == 4096)
  __shared__ double red[NE];

  const int tid = threadIdx.x;
  const int e   = tid & 127;
  const int h   = tid >> 7;
  const int count = cnt[0];

  for (int i = blockIdx.x; i < count; i += gridDim.x) {
    const int t = flags[i];

    __syncthreads();
    {
      const float* xp = x + (size_t)t * H;
#pragma unroll
      for (int c = 0; c < 4; ++c) {
        const int fi = (c * 256 + tid) * 4;
        *(float4*)(xs + fi) = *(const float4*)(xp + fi);
      }
    }
    __syncthreads();

    double a0 = 0.0, a1 = 0.0, a2 = 0.0, a3 = 0.0;
    {
      const float* wp = W + (size_t)e * H + h * 2048;
      const float* xb = xs + h * 2048;
      for (int kk = 0; kk < 2048; kk += 4) {
        const float4 wv = *(const float4*)(wp + kk);
        const float4 xv = *(const float4*)(xb + kk);
        a0 = fma((double)xv.x, (double)wv.x, a0);
        a1 = fma((double)xv.y, (double)wv.y, a1);
        a2 = fma((double)xv.z, (double)wv.z, a2);
        a3 = fma((double)xv.w, (double)wv.w, a3);
      }
    }
    const double a = (a0 + a1) + (a2 + a3);

    if (h == 1) red[e] = a;
    __syncthreads();
    if (h == 0) red[e] = 1.0 / (1.0 + exp(-(a + red[e])));
    __syncthreads();

    if (tid < 64) {
      const int l = tid;
      const double s0 = red[l];
      const double s1 = red[64 + l];
      double g0 = s0 + (double)bias[l];
      double g1 = s1 + (double)bias[64 + l];
      double myw[TOPK]; int myid[TOPK];
#pragma unroll
      for (int r = 0; r < TOPK; ++r) {
        double bv; int bi;
        if (g1 > g0) { bv = g1; bi = 64 + l; } else { bv = g0; bi = l; }
#pragma unroll
        for (int m = 1; m <= 32; m <<= 1) {
          const double ov = __shfl_xor(bv, m);
          const int    oi = __shfl_xor(bi, m);
          if (ov > bv || (ov == bv && oi < bi)) { bv = ov; bi = oi; }
        }
        const int ls   = bi & 63;
        const int slot = bi >> 6;
        const double sv = slot ? s1 : s0;
        const double sw = __shfl(sv, ls);
        myw[r]  = sw;
        myid[r] = bi;
        if (l == ls) { if (slot) g1 = -INFINITY; else g0 = -INFINITY; }
      }
      if (l == 0) {
        double den = 0.0;
#pragma unroll
        for (int r = 0; r < TOPK; ++r) den += fabs(myw[r]);
        den = fmax(den, 1e-12);
#pragma unroll
        for (int r = 0; r < TOPK; ++r) {
          out_w[(size_t)t * TOPK + r] = (float)(myw[r] / den);
          out_i[(size_t)t * TOPK + r] = (float)myid[r];
        }
      }
    }
  }
}

extern "C" void kernel_launch(void* const* d_in, const int* in_sizes, int n_in,
                              void* d_out, int out_size, void* d_ws, size_t ws_size,
                              hipStream_t stream) {
  const float* x    = (const float*)d_in[0];
  const float* W    = (const float*)d_in[1];
  const float* bias = (const float*)d_in[2];
  const int E = in_sizes[2];            // 128
  const int H = in_sizes[1] / E;        // 4096
  const int T = in_sizes[0] / H;        // 32768
  (void)E; (void)n_in; (void)ws_size; (void)out_size;

  float* out_w = (float*)d_out;
  float* out_i = out_w + (size_t)T * TOPK;

  // workspace layout (bytes): whi [1MB] | wlo [1MB] | mask [4KB] | cnt [16B] | flags
  char* ws = (char*)d_ws;
  _Float16* whi = (_Float16*)ws;
  _Float16* wlo = (_Float16*)(ws + (1 << 20));
  unsigned int* mask = (unsigned int*)(ws + (2 << 20));
  const int nwords = (T + 31) / 32;     // 1024
  int* cnt   = (int*)(ws + (2 << 20) + nwords * 4);
  int* flags = (int*)(ws + (2 << 20) + nwords * 4 + 16);

  const int n4 = (E * H) / 4;           // 131072 float4s
  router_wsplit<<<dim3((n4 + 255) / 256), dim3(256), 0, stream>>>(W, whi, wlo, n4);
  router_pass1<<<dim3(T / 64), dim3(512), 0, stream>>>(x, whi, wlo, bias, out_w, out_i, mask, T, H);
  router_compact<<<dim3(1), dim3(1024), 0, stream>>>(mask, cnt, flags, nwords);
  router_pass2<<<dim3(2048), dim3(256), 0, stream>>>(x, W, bias, out_w, out_i, cnt, flags, H);
}

// Round 22
// 239.277 us; speedup vs baseline: 1.1252x; 1.1252x over previous
//
#include <hip/hip_runtime.h>
#include <math.h>

#define TOPK 8
#define NE   128
#define MARGIN 1e-5f

typedef _Float16 h8 __attribute__((ext_vector_type(8)));
typedef _Float16 h4 __attribute__((ext_vector_type(4)));
typedef float    f4 __attribute__((ext_vector_type(4)));

// byte address within a [row][64 halfs] LDS tile (128 B row stride),
// XOR-swizzled so 16-lane column reads spread across banks. (R8-validated)
__device__ __forceinline__ int swz(int row, int kb) {
  return row * 128 + (kb ^ ((row & 7) << 4));
}

#define GLOAD_LDS16(g, l)                                              \
  __builtin_amdgcn_global_load_lds(                                    \
      (const __attribute__((address_space(1))) void*)(g),              \
      (__attribute__((address_space(3))) void*)(l), 16, 0, 0)

// ---------------- Kernel 0: split W into fp16 hi + scaled lo ----------------
__global__ __launch_bounds__(256) void router_wsplit(
    const float* __restrict__ W, _Float16* __restrict__ whi,
    _Float16* __restrict__ wlo, int n4) {
  const int i = blockIdx.x * 256 + threadIdx.x;
  if (i < n4) {
    const float4 v = ((const float4*)W)[i];
    h4 hi, lo;
#pragma unroll
    for (int q = 0; q < 4; ++q) {
      const float vq = ((const float*)&v)[q];
      const _Float16 h = (_Float16)vq;
      hi[q] = h;
      lo[q] = (_Float16)((vq - (float)h) * 2048.0f);  // lo' = lo * 2^11
    }
    ((h4*)whi)[i] = hi;
    ((h4*)wlo)[i] = lo;
  }
}

// ---------------- Pass 1: split-fp16 MFMA GEMM, counted-vmcnt pipeline ----------------
// 512 threads = 8 waves; tile 64 tok x 128 exp; BK=64; 80KB LDS -> 2 blocks/CU.
// B double-buffered via global_load_lds (issued 1 tile ahead, drained next
// barrier1 via counted vmcnt). px (x prefetch) 2 tiles deep (two named sets,
// loop unrolled x2 for static indexing). Raw s_barrier: loads fly across.
__global__ __launch_bounds__(512, 2) void router_pass1(
    const float* __restrict__ x,        // [T, H] fp32
    const _Float16* __restrict__ whi,   // [E, H] fp16
    const _Float16* __restrict__ wlo,   // [E, H] fp16 (x 2^11)
    const float* __restrict__ bias,
    float* __restrict__ out_w, float* __restrict__ out_i,
    unsigned int* __restrict__ mask, int T, int H) {
  __shared__ char lds[81920];
  // A_hi @0 (8KB), A_lo @8192; B buf0: hi @16384, lo @32768;
  // B buf1: hi @49152, lo @65536. Epilogue: logits [64][132] f32 @0, flg @33792.

  const int tid = threadIdx.x;
  const int t0  = blockIdx.x * 64;
  const int l   = tid & 63;
  const int wv  = tid >> 6;            // 0..7
  const int wm  = wv & 1;              // token half (32)
  const int wn  = wv >> 1;             // expert quarter (32)

  // x staging: thread -> row tid>>3 (0..63), k-octet (tid&7)*8
  const int xrow = tid >> 3;
  const float* xptr = x + (size_t)(t0 + xrow) * H + (tid & 7) * 8;
  const int aw = swz(xrow, (tid & 7) * 16);   // A write byte-addr (hi; lo at +8192)

  // W DMA: 2 chunks/thread per 16KB component; pre-swizzled source (R8-validated).
  int soff0, soff1;
  {
    const int o0  = (wv * 2) * 1024 + l * 16;
    const int r0  = o0 >> 7;
    soff0 = r0 * (H * 2) + ((o0 & 127) ^ ((r0 & 7) << 4));
    const int o1  = (wv * 2 + 1) * 1024 + l * 16;
    const int r1  = o1 >> 7;
    soff1 = r1 * (H * 2) + ((o1 & 127) ^ ((r1 & 7) << 4));
  }
  const int dst0 = (wv * 2) * 1024;
  const int dst1 = (wv * 2 + 1) * 1024;

  f4 acc1[2][2], acc2[2][2];
#pragma unroll
  for (int mt = 0; mt < 2; ++mt)
#pragma unroll
    for (int nt = 0; nt < 2; ++nt) { acc1[mt][nt] = (f4)0.0f; acc2[mt][nt] = (f4)0.0f; }

  // ---- prologue: WDMA tile0 -> buf0; px setA <- tile0, setB <- tile1 ----
  GLOAD_LDS16((const char*)whi + soff0, lds + 16384 + dst0);
  GLOAD_LDS16((const char*)whi + soff1, lds + 16384 + dst1);
  GLOAD_LDS16((const char*)wlo + soff0, lds + 32768 + dst0);
  GLOAD_LDS16((const char*)wlo + soff1, lds + 32768 + dst1);
  float4 pxA0 = *(const float4*)(xptr);
  float4 pxA1 = *(const float4*)(xptr + 4);
  float4 pxB0 = *(const float4*)(xptr + 64);
  float4 pxB1 = *(const float4*)(xptr + 68);

#define ITER(K0, PX0, PX1, CUR)                                               \
  {                                                                           \
    /* barrier1: drain WDMA(K0)+px(K0), keep newest px pair in flight */      \
    if ((K0) + 64 < H)                                                        \
      asm volatile("s_waitcnt vmcnt(2) lgkmcnt(0)" ::: "memory");             \
    else                                                                      \
      asm volatile("s_waitcnt vmcnt(0) lgkmcnt(0)" ::: "memory");             \
    __builtin_amdgcn_s_barrier();                                             \
    __builtin_amdgcn_sched_barrier(0);                                        \
    /* issue WDMA(K0+64) -> other buf (drained at NEXT barrier1) */           \
    if ((K0) + 64 < H) {                                                      \
      const char* whb = (const char*)whi + (size_t)((K0) + 64) * 2;           \
      const char* wlb = (const char*)wlo + (size_t)((K0) + 64) * 2;           \
      const int nb = 16384 + ((CUR) ^ 1) * 32768;                             \
      GLOAD_LDS16(whb + soff0, lds + nb + dst0);                              \
      GLOAD_LDS16(whb + soff1, lds + nb + dst1);                              \
      GLOAD_LDS16(wlb + soff0, lds + nb + 16384 + dst0);                      \
      GLOAD_LDS16(wlb + soff1, lds + nb + 16384 + dst1);                      \
    }                                                                         \
    { /* convert px(K0) -> A hi/lo, one b128 write each */                    \
      h8 hi, lo;                                                              \
      const float* pv0 = (const float*)&PX0;                                  \
      const float* pv1 = (const float*)&PX1;                                  \
      _Pragma("unroll")                                                       \
      for (int q = 0; q < 4; ++q) {                                           \
        const _Float16 h0 = (_Float16)pv0[q];                                 \
        const _Float16 h1 = (_Float16)pv1[q];                                 \
        hi[q] = h0; hi[4 + q] = h1;                                           \
        lo[q]     = (_Float16)((pv0[q] - (float)h0) * 2048.0f);               \
        lo[4 + q] = (_Float16)((pv1[q] - (float)h1) * 2048.0f);               \
      }                                                                       \
      *(h8*)(lds + aw)        = hi;                                           \
      *(h8*)(lds + 8192 + aw) = lo;                                           \
    }                                                                         \
    /* reload this px set 2 tiles ahead */                                    \
    if ((K0) + 128 < H) {                                                     \
      PX0 = *(const float4*)(xptr + (K0) + 128);                              \
      PX1 = *(const float4*)(xptr + (K0) + 132);                              \
    }                                                                         \
    /* barrier2: A writes visible; NO vm drain (DMA/px stay in flight) */     \
    asm volatile("s_waitcnt lgkmcnt(0)" ::: "memory");                        \
    __builtin_amdgcn_s_barrier();                                             \
    __builtin_amdgcn_sched_barrier(0);                                        \
    { /* MFMA from A + B[CUR] */                                              \
      const int bhi = 16384 + (CUR) * 32768;                                  \
      _Pragma("unroll")                                                       \
      for (int ks = 0; ks < 2; ++ks) {                                        \
        const int kb = ks * 64 + ((l >> 4) * 16);                             \
        h8 Ah[2], Al[2];                                                      \
        _Pragma("unroll")                                                     \
        for (int mt = 0; mt < 2; ++mt) {                                      \
          const int row = wm * 32 + mt * 16 + (l & 15);                       \
          Ah[mt] = *(const h8*)(lds +        swz(row, kb));                   \
          Al[mt] = *(const h8*)(lds + 8192 + swz(row, kb));                   \
        }                                                                     \
        _Pragma("unroll")                                                     \
        for (int nt = 0; nt < 2; ++nt) {                                      \
          const int er = wn * 32 + nt * 16 + (l & 15);                        \
          const h8 Bh = *(const h8*)(lds + bhi         + swz(er, kb));        \
          const h8 Bl = *(const h8*)(lds + bhi + 16384 + swz(er, kb));        \
          _Pragma("unroll")                                                   \
          for (int mt = 0; mt < 2; ++mt) {                                    \
            acc1[mt][nt] = __builtin_amdgcn_mfma_f32_16x16x32_f16(Ah[mt], Bh, acc1[mt][nt], 0, 0, 0); \
            acc2[mt][nt] = __builtin_amdgcn_mfma_f32_16x16x32_f16(Ah[mt], Bl, acc2[mt][nt], 0, 0, 0); \
            acc2[mt][nt] = __builtin_amdgcn_mfma_f32_16x16x32_f16(Al[mt], Bh, acc2[mt][nt], 0, 0, 0); \
          }                                                                   \
        }                                                                     \
      }                                                                       \
    }                                                                         \
  }

  for (int k0 = 0; k0 < H; k0 += 128) {
    ITER(k0,      pxA0, pxA1, 0)
    ITER(k0 + 64, pxB0, pxB1, 1)
  }
#undef ITER

  // ---- dump logits to LDS (C/D layout: col=lane&15, row=(lane>>4)*4+r) ----
  __syncthreads();
  float* logits = (float*)lds;
  unsigned char* flg = (unsigned char*)(lds + 33792);
#pragma unroll
  for (int mt = 0; mt < 2; ++mt)
#pragma unroll
    for (int nt = 0; nt < 2; ++nt)
#pragma unroll
      for (int r = 0; r < 4; ++r) {
        const int row = wm * 32 + mt * 16 + (l >> 4) * 4 + r;
        const int col = wn * 32 + nt * 16 + (l & 15);
        logits[row * 132 + col] = acc1[mt][nt][r] + acc2[mt][nt][r] * (1.0f / 2048.0f);
      }
  __syncthreads();

  // ---- epilogue: sigmoid, top-8 across 16-lane groups, flag near-ties ----
  const int tx    = tid & 15;
  const int g     = tid >> 4;          // 32 groups x 2 tokens
  const int lane  = tid & 63;
  const int gbase = lane & 48;

  float biasr[8];
#pragma unroll
  for (int j = 0; j < 4; ++j) {
    biasr[j]     = bias[tx * 4 + j];
    biasr[4 + j] = bias[64 + tx * 4 + j];
  }

#pragma unroll
  for (int it = 0; it < 2; ++it) {
    const int tok = g * 2 + it;
    const float4 lo4 = *(const float4*)(logits + tok * 132 + tx * 4);
    const float4 hi4 = *(const float4*)(logits + tok * 132 + 64 + tx * 4);
    float sc[8], bal[8];
#pragma unroll
    for (int j = 0; j < 4; ++j) {
      sc[j]     = 1.f / (1.f + expf(-((const float*)&lo4)[j]));
      sc[4 + j] = 1.f / (1.f + expf(-((const float*)&hi4)[j]));
    }
#pragma unroll
    for (int j = 0; j < 8; ++j) bal[j] = sc[j] + biasr[j];

    float myw[TOPK];
    int   myid[TOPK];
    float prev = 0.f;
    int   flagged = 0;
#pragma unroll
    for (int r = 0; r < TOPK + 1; ++r) {
      float bv = bal[0];
      int   bi = tx * 4;
#pragma unroll
      for (int j = 1; j < 8; ++j) {
        const int ej = (j < 4) ? (tx * 4 + j) : (64 + tx * 4 + (j - 4));
        if (bal[j] > bv) { bv = bal[j]; bi = ej; }
      }
#pragma unroll
      for (int m = 1; m <= 8; m <<= 1) {
        const float ov = __shfl_xor(bv, m);
        const int   oi = __shfl_xor(bi, m);
        if (ov > bv || (ov == bv && oi < bi)) { bv = ov; bi = oi; }
      }
      if (r > 0 && (prev - bv) < MARGIN) flagged = 1;
      prev = bv;
      if (r < TOPK) {
        const int ls = (bi < 64) ? (bi >> 2) : ((bi - 64) >> 2);
        const int jt = (bi < 64) ? (bi & 3) : (4 + ((bi - 64) & 3));
        const float a0s = (jt & 1) ? sc[1] : sc[0];
        const float a1s = (jt & 1) ? sc[3] : sc[2];
        const float a2s = (jt & 1) ? sc[5] : sc[4];
        const float a3s = (jt & 1) ? sc[7] : sc[6];
        const float b0s = (jt & 2) ? a1s : a0s;
        const float b1s = (jt & 2) ? a3s : a2s;
        const float sv = (jt & 4) ? b1s : b0s;
        const float sw = __shfl(sv, gbase | ls);
        myw[r]  = sw;
        myid[r] = bi;
#pragma unroll
        for (int j = 0; j < 8; ++j)
          if (tx == ls && j == jt) bal[j] = -INFINITY;
      }
    }

    if (tx == 0) {
      float den = 0.f;
#pragma unroll
      for (int r = 0; r < TOPK; ++r) den += fabsf(myw[r]);
      den = fmaxf(den, 1e-12f);
      const int t = t0 + tok;
      float4* wo = (float4*)(out_w + (size_t)t * TOPK);
      float4* io = (float4*)(out_i + (size_t)t * TOPK);
      wo[0] = make_float4(myw[0] / den, myw[1] / den, myw[2] / den, myw[3] / den);
      wo[1] = make_float4(myw[4] / den, myw[5] / den, myw[6] / den, myw[7] / den);
      io[0] = make_float4((float)myid[0], (float)myid[1], (float)myid[2], (float)myid[3]);
      io[1] = make_float4((float)myid[4], (float)myid[5], (float)myid[6], (float)myid[7]);
      flg[tok] = (unsigned char)flagged;
    }
  }

  // ---- assemble and store this block's two mask words (no atomics) ----
  __syncthreads();
  if (tid < 2) {
    unsigned int wbits = 0;
#pragma unroll
    for (int b = 0; b < 32; ++b)
      wbits |= (flg[tid * 32 + b] ? 1u : 0u) << b;
    mask[blockIdx.x * 2 + tid] = wbits;
  }
}

// ---------------- Compaction: bitmask -> ordered token list (deterministic) ----------------
__global__ __launch_bounds__(1024) void router_compact(
    const unsigned int* __restrict__ mask, int* __restrict__ cnt,
    int* __restrict__ flags, int nwords) {
  __shared__ int wsum[17];
  const int tid = threadIdx.x;
  unsigned int w = (tid < nwords) ? mask[tid] : 0u;
  const int c = __popc(w);
  const int lane = tid & 63;
  const int wv   = tid >> 6;
  int inc = c;
#pragma unroll
  for (int m = 1; m < 64; m <<= 1) {
    const int v = __shfl_up(inc, m);
    if (lane >= m) inc += v;
  }
  if (lane == 63) wsum[wv + 1] = inc;
  __syncthreads();
  if (tid == 0) {
    wsum[0] = 0;
    for (int i = 1; i <= 16; ++i) wsum[i] += wsum[i - 1];
    cnt[0] = wsum[16];
  }
  __syncthreads();
  int off = wsum[wv] + inc - c;
  while (w) {
    const int b = __ffs(w) - 1;
    w &= w - 1u;
    flags[off++] = tid * 32 + b;
  }
}

// ---------------- Pass 2: fp64 recompute, ONE token per block (grid-stride) ----------------
__global__ __launch_bounds__(256) void router_pass2(
    const float* __restrict__ x, const float* __restrict__ W,
    const float* __restrict__ bias,
    float* __restrict__ out_w, float* __restrict__ out_i,
    const int* __restrict__ cnt, const int* __restrict__ flags, int H) {
  __shared__ float  xs[4096];          // 16 KB (H == 4096)
  __shared__ double red[NE];

  const int tid = threadIdx.x;
  const int e   = tid & 127;
  const int h   = tid >> 7;
  const int count = cnt[0];

  for (int i = blockIdx.x; i < count; i += gridDim.x) {
    const int t = flags[i];

    __syncthreads();
    {
      const float* xp = x + (size_t)t * H;
#pragma unroll
      for (int c = 0; c < 4; ++c) {
        const int fi = (c * 256 + tid) * 4;
        *(float4*)(xs + fi) = *(const float4*)(xp + fi);
      }
    }
    __syncthreads();

    double a0 = 0.0, a1 = 0.0, a2 = 0.0, a3 = 0.0;
    {
      const float* wp = W + (size_t)e * H + h * 2048;
      const float* xb = xs + h * 2048;
      for (int kk = 0; kk < 2048; kk += 4) {
        const float4 wv = *(const float4*)(wp + kk);
        const float4 xv = *(const float4*)(xb + kk);
        a0 = fma((double)xv.x, (double)wv.x, a0);
        a1 = fma((double)xv.y, (double)wv.y, a1);
        a2 = fma((double)xv.z, (double)wv.z, a2);
        a3 = fma((double)xv.w, (double)wv.w, a3);
      }
    }
    const double a = (a0 + a1) + (a2 + a3);

    if (h == 1) red[e] = a;
    __syncthreads();
    if (h == 0) red[e] = 1.0 / (1.0 + exp(-(a + red[e])));
    __syncthreads();

    if (tid < 64) {
      const int l = tid;
      const double s0 = red[l];
      const double s1 = red[64 + l];
      double g0 = s0 + (double)bias[l];
      double g1 = s1 + (double)bias[64 + l];
      double myw[TOPK]; int myid[TOPK];
#pragma unroll
      for (int r = 0; r < TOPK; ++r) {
        double bv; int bi;
        if (g1 > g0) { bv = g1; bi = 64 + l; } else { bv = g0; bi = l; }
#pragma unroll
        for (int m = 1; m <= 32; m <<= 1) {
          const double ov = __shfl_xor(bv, m);
          const int    oi = __shfl_xor(bi, m);
          if (ov > bv || (ov == bv && oi < bi)) { bv = ov; bi = oi; }
        }
        const int ls   = bi & 63;
        const int slot = bi >> 6;
        const double sv = slot ? s1 : s0;
        const double sw = __shfl(sv, ls);
        myw[r]  = sw;
        myid[r] = bi;
        if (l == ls) { if (slot) g1 = -INFINITY; else g0 = -INFINITY; }
      }
      if (l == 0) {
        double den = 0.0;
#pragma unroll
        for (int r = 0; r < TOPK; ++r) den += fabs(myw[r]);
        den = fmax(den, 1e-12);
#pragma unroll
        for (int r = 0; r < TOPK; ++r) {
          out_w[(size_t)t * TOPK + r] = (float)(myw[r] / den);
          out_i[(size_t)t * TOPK + r] = (float)myid[r];
        }
      }
    }
  }
}

extern "C" void kernel_launch(void* const* d_in, const int* in_sizes, int n_in,
                              void* d_out, int out_size, void* d_ws, size_t ws_size,
                              hipStream_t stream) {
  const float* x    = (const float*)d_in[0];
  const float* W    = (const float*)d_in[1];
  const float* bias = (const float*)d_in[2];
  const int E = in_sizes[2];            // 128
  const int H = in_sizes[1] / E;        // 4096
  const int T = in_sizes[0] / H;        // 32768
  (void)E; (void)n_in; (void)ws_size; (void)out_size;

  float* out_w = (float*)d_out;
  float* out_i = out_w + (size_t)T * TOPK;

  // workspace layout (bytes): whi [1MB] | wlo [1MB] | mask [4KB] | cnt [16B] | flags
  char* ws = (char*)d_ws;
  _Float16* whi = (_Float16*)ws;
  _Float16* wlo = (_Float16*)(ws + (1 << 20));
  unsigned int* mask = (unsigned int*)(ws + (2 << 20));
  const int nwords = (T + 31) / 32;     // 1024
  int* cnt   = (int*)(ws + (2 << 20) + nwords * 4);
  int* flags = (int*)(ws + (2 << 20) + nwords * 4 + 16);

  const int n4 = (E * H) / 4;           // 131072 float4s
  router_wsplit<<<dim3((n4 + 255) / 256), dim3(256), 0, stream>>>(W, whi, wlo, n4);
  router_pass1<<<dim3(T / 64), dim3(512), 0, stream>>>(x, whi, wlo, bias, out_w, out_i, mask, T, H);
  router_compact<<<dim3(1), dim3(1024), 0, stream>>>(mask, cnt, flags, nwords);
  router_pass2<<<dim3(2048), dim3(256), 0, stream>>>(x, W, bias, out_w, out_i, cnt, flags, H);
}